// Round 4
// baseline (43.019 us; speedup 1.0000x reference)
//
#include <hip/hip_runtime.h>
#include <hip/hip_bf16.h>

// TrajectoryInformedSplatAttention — two-kernel streaming split.
// B=4, S=4096, D=1024, maxd=8.
//
// K1 (mag):   per diff i: mag = ||emb[i+1]-emb[i]||; write magw = tanh(2*mag),
//             q = magw/mag (0 if mag<=1e-6) into d_ws.   Pure HBM read stream.
// K2 (splat): traj[b,s,:] = sum_{jr=0..8} g[s][jr]*emb[b,s-8+jr,:] (telescoped),
//             g from magw/q. Reads are L3-resident after K1 -> write-bound.

constexpr int B_ = 4;
constexpr int S_ = 4096;
constexpr int D_ = 1024;
constexpr int MAXD = 8;
constexpr int NDIFF_TOT = S_ - 1;            // 4095 diffs per batch

// ---------------- K1: magnitudes ----------------
constexpr int K1_CHUNK = 32;                 // diffs per block

__global__ __launch_bounds__(256, 2)
void mag_kernel(const float* __restrict__ emb,
                float* __restrict__ magw_g, float* __restrict__ q_g) {
    const int r0 = blockIdx.x * K1_CHUNK;    // first diff index
    const int b  = blockIdx.y;
    const int lane = threadIdx.x & 63;
    const int wave = threadIdx.x >> 6;
    const int d0   = threadIdx.x * 4;

    const float* __restrict__ embB = emb + (size_t)b * S_ * D_;

    __shared__ float part[K1_CHUNK][4][4];

    // 33-row register window (independent loads, ILP)
    float4 win[K1_CHUNK + 1];
    #pragma unroll
    for (int r = 0; r <= K1_CHUNK; ++r) {
        const int row = r0 + r;
        if (row < S_)
            win[r] = *(const float4*)(embB + (size_t)row * D_ + d0);
        else
            win[r] = make_float4(0.f, 0.f, 0.f, 0.f);
    }

    #pragma unroll
    for (int li = 0; li < K1_CHUNK; ++li) {
        const float4 a = win[li], c = win[li + 1];
        const float dx = c.x - a.x, dy = c.y - a.y;
        const float dz = c.z - a.z, dw = c.w - a.w;
        float sum = dx * dx + dy * dy + dz * dz + dw * dw;
        sum += __shfl_xor(sum, 32, 64);
        sum += __shfl_xor(sum, 16, 64);
        sum += __shfl_xor(sum,  8, 64);
        sum += __shfl_xor(sum,  4, 64);
        if (lane < 4) part[li][wave][lane] = sum;
    }
    __syncthreads();

    if (threadIdx.x < K1_CHUNK) {
        const int li = threadIdx.x;
        const int d  = r0 + li;
        if (d < NDIFF_TOT) {
            float s2 = 0.f;
            #pragma unroll
            for (int w = 0; w < 4; ++w)
                #pragma unroll
                for (int k = 0; k < 4; ++k)
                    s2 += part[li][w][k];
            const float mag = sqrtf(s2);
            const float mw  = tanhf(2.f * mag);
            const size_t o  = (size_t)b * NDIFF_TOT + d;
            magw_g[o] = mw;
            q_g[o]    = (mag > 1e-6f) ? (mw / mag) : 0.f;
        }
    }
}

// ---------------- K2: splat ----------------
constexpr int CHUNK2  = 16;
constexpr int ROWS2   = CHUNK2 + MAXD;       // 24-row window
constexpr int NCHUNK2 = S_ / CHUNK2;         // 256 per batch
constexpr int NWG2    = NCHUNK2 * B_;        // 1024 blocks
constexpr int NXCD    = 8;

__global__ __launch_bounds__(256, 3)
void splat_kernel(const float* __restrict__ emb,
                  const float* __restrict__ magw_g, const float* __restrict__ q_g,
                  float* __restrict__ out) {
    // XCD-aware swizzle (NWG2 % 8 == 0 -> bijective): neighbor s-chunks share
    // their 8-row halo in the same XCD's L2.
    const int bid = blockIdx.x;
    const int lin = (bid % NXCD) * (NWG2 / NXCD) + bid / NXCD;
    const int schunk = lin & (NCHUNK2 - 1);
    const int b      = lin >> 8;             // lin / 256

    const int s0 = schunk * CHUNK2;
    const int d0 = threadIdx.x * 4;

    const float* __restrict__ embB = emb + (size_t)b * S_ * D_;

    __shared__ float gco[CHUNK2][12];        // 9 coefs padded to 12 floats

    // Issue the 24 window loads FIRST (latency hides under coefficient build)
    float4 win[ROWS2];
    #pragma unroll
    for (int r = 0; r < ROWS2; ++r) {
        const int row = s0 - MAXD + r;       // max = s0+15 <= S-1
        if (row >= 0)
            win[r] = *(const float4*)(embB + (size_t)row * D_ + d0);
        else
            win[r] = make_float4(0.f, 0.f, 0.f, 0.f);
    }

    // 16 threads build the 9 telescoped coefficients per s from global scalars
    if (threadIdx.x < CHUNK2) {
        const int sl = threadIdx.x;
        const int s  = s0 + sl;
        const int ws = min(MAXD, s);
        const int lo = MAXD - ws;
        const float rden = 0.9f / (float)max(ws - 1, 1);
        const size_t bD  = (size_t)b * NDIFF_TOT;

        float cpad[MAXD + 2];
        #pragma unroll
        for (int t = 0; t < MAXD + 2; ++t) cpad[t] = 0.f;

        float wsum = 0.f;
        #pragma unroll
        for (int j = 0; j < MAXD; ++j) {
            if (j >= lo) {
                const int d = s - MAXD + j;  // global diff index, in [0, S-2]
                const float lin2 = (ws > 1) ? (0.1f + rden * (float)(j - lo)) : 0.1f;
                wsum += lin2 * magw_g[bD + d];
                cpad[j + 1] = lin2 * q_g[bD + d];
            }
        }
        const float inv = 1.f / fmaxf(wsum, 1e-8f);
        #pragma unroll
        for (int jr = 0; jr <= MAXD; ++jr)
            gco[sl][jr] = (cpad[jr] - cpad[jr + 1]) * inv;
    }
    __syncthreads();

    float* outB = out + ((size_t)b * S_ + s0) * D_ + d0;
    #pragma unroll
    for (int sl = 0; sl < CHUNK2; ++sl) {
        const float4 g0 = *(const float4*)&gco[sl][0];
        const float4 g1 = *(const float4*)&gco[sl][4];
        const float  g8 = gco[sl][8];

        float4 acc;
        acc.x = g0.x * win[sl].x; acc.y = g0.x * win[sl].y;
        acc.z = g0.x * win[sl].z; acc.w = g0.x * win[sl].w;
        const float gs[8] = {g0.y, g0.z, g0.w, g1.x, g1.y, g1.z, g1.w, g8};
        #pragma unroll
        for (int jr = 1; jr <= MAXD; ++jr) {
            const float g = gs[jr - 1];
            acc.x += g * win[sl + jr].x;
            acc.y += g * win[sl + jr].y;
            acc.z += g * win[sl + jr].z;
            acc.w += g * win[sl + jr].w;
        }
        *(float4*)(outB + (size_t)sl * D_) = acc;
    }
}

// ---------------- Fallback: proven R3 single-kernel (if ws too small) ----------------
constexpr int FCHUNK = 32;
constexpr int FROWS  = FCHUNK + MAXD;
constexpr int FNDIFF = FROWS - 1;
constexpr int FNCH   = S_ / FCHUNK;
constexpr int FNWG   = FNCH * B_;

__global__ __launch_bounds__(256, 2)
void traj_splat_fallback(const float* __restrict__ emb, float* __restrict__ out) {
    const int bid = blockIdx.x;
    const int lin = (bid % NXCD) * (FNWG / NXCD) + bid / NXCD;
    const int schunk = lin & (FNCH - 1);
    const int b      = lin >> 7;

    const int s0   = schunk * FCHUNK;
    const int lane = threadIdx.x & 63;
    const int wave = threadIdx.x >> 6;
    const int d0   = threadIdx.x * 4;

    const float* __restrict__ embB = emb + (size_t)b * S_ * D_;

    __shared__ float part[FNDIFF][4][4];
    __shared__ float smagw[FNDIFF];
    __shared__ float sq[FNDIFF];
    __shared__ float gco[FCHUNK][12];

    float4 win[FROWS];
    #pragma unroll
    for (int r = 0; r < FROWS; ++r) {
        const int row = s0 - MAXD + r;
        if (row >= 0)
            win[r] = *(const float4*)(embB + (size_t)row * D_ + d0);
        else
            win[r] = make_float4(0.f, 0.f, 0.f, 0.f);
    }

    #pragma unroll
    for (int li = 0; li < FNDIFF; ++li) {
        const float4 a = win[li], c = win[li + 1];
        const float dx = c.x - a.x, dy = c.y - a.y;
        const float dz = c.z - a.z, dw = c.w - a.w;
        float sum = dx * dx + dy * dy + dz * dz + dw * dw;
        sum += __shfl_xor(sum, 32, 64);
        sum += __shfl_xor(sum, 16, 64);
        sum += __shfl_xor(sum,  8, 64);
        sum += __shfl_xor(sum,  4, 64);
        if (lane < 4) part[li][wave][lane] = sum;
    }
    __syncthreads();

    if (threadIdx.x < FNDIFF) {
        const int li = threadIdx.x;
        float s2 = 0.f;
        #pragma unroll
        for (int w = 0; w < 4; ++w)
            #pragma unroll
            for (int k = 0; k < 4; ++k)
                s2 += part[li][w][k];
        const float mag = sqrtf(s2);
        const float mw  = tanhf(2.f * mag);
        smagw[li] = mw;
        sq[li]    = (mag > 1e-6f) ? (mw / mag) : 0.f;
    }
    __syncthreads();

    if (threadIdx.x < FCHUNK) {
        const int sl = threadIdx.x;
        const int s  = s0 + sl;
        const int ws = min(MAXD, s);
        const int lo = MAXD - ws;
        const float rden = 0.9f / (float)max(ws - 1, 1);

        float cpad[MAXD + 2];
        #pragma unroll
        for (int t = 0; t < MAXD + 2; ++t) cpad[t] = 0.f;

        float wsum = 0.f;
        #pragma unroll
        for (int j = 0; j < MAXD; ++j) {
            if (j >= lo) {
                const int li = sl + j;
                const float lin2 = (ws > 1) ? (0.1f + rden * (float)(j - lo)) : 0.1f;
                wsum += lin2 * smagw[li];
                cpad[j + 1] = lin2 * sq[li];
            }
        }
        const float inv = 1.f / fmaxf(wsum, 1e-8f);
        #pragma unroll
        for (int jr = 0; jr <= MAXD; ++jr)
            gco[sl][jr] = (cpad[jr] - cpad[jr + 1]) * inv;
    }
    __syncthreads();

    float* outB = out + ((size_t)b * S_ + s0) * D_ + d0;
    #pragma unroll
    for (int sl = 0; sl < FCHUNK; ++sl) {
        const float4 g0 = *(const float4*)&gco[sl][0];
        const float4 g1 = *(const float4*)&gco[sl][4];
        const float  g8 = gco[sl][8];

        float4 acc;
        acc.x = g0.x * win[sl].x; acc.y = g0.x * win[sl].y;
        acc.z = g0.x * win[sl].z; acc.w = g0.x * win[sl].w;
        const float gs[8] = {g0.y, g0.z, g0.w, g1.x, g1.y, g1.z, g1.w, g8};
        #pragma unroll
        for (int jr = 1; jr <= MAXD; ++jr) {
            const float g = gs[jr - 1];
            acc.x += g * win[sl + jr].x;
            acc.y += g * win[sl + jr].y;
            acc.z += g * win[sl + jr].z;
            acc.w += g * win[sl + jr].w;
        }
        *(float4*)(outB + (size_t)sl * D_) = acc;
    }
}

extern "C" void kernel_launch(void* const* d_in, const int* in_sizes, int n_in,
                              void* d_out, int out_size, void* d_ws, size_t ws_size,
                              hipStream_t stream) {
    const float* emb = (const float*)d_in[0];
    float* out = (float*)d_out;

    const size_t need = 2 * (size_t)B_ * NDIFF_TOT * sizeof(float);  // ~131 KB
    if (ws_size >= need) {
        float* magw_g = (float*)d_ws;
        float* q_g    = magw_g + (size_t)B_ * NDIFF_TOT;

        dim3 g1(S_ / K1_CHUNK, B_);          // 128 x 4 = 512 blocks
        mag_kernel<<<g1, dim3(256), 0, stream>>>(emb, magw_g, q_g);

        dim3 g2(NWG2);                       // 1024 blocks
        splat_kernel<<<g2, dim3(256), 0, stream>>>(emb, magw_g, q_g, out);
    } else {
        dim3 g(FNWG);                        // 512 blocks
        traj_splat_fallback<<<g, dim3(256), 0, stream>>>(emb, out);
    }
}

// Round 6
// 29.228 us; speedup vs baseline: 1.4719x; 1.4719x over previous
//
#include <hip/hip_runtime.h>
#include <hip/hip_bf16.h>

// TrajectoryInformedSplatAttention — single-kernel, 512-thread blocks (float2).
// B=4, S=4096, D=1024, maxd=8.
//
// traj[b,s,:] = sum_{jr=0..8} g[s][jr] * emb[b, s-8+jr, :]   (telescoped)
//   g[jr] = (c[jr-1]-c[jr])/wsum, c[j] = lin(s,j)*q[i], i=s-8+j
//   q = tanh(2*mag)/mag (0 if mag<=1e-6), wsum = max(sum lin*tanh(2*mag),1e-8)
//
// Full D stays in ONE block (mag is a full-D reduction — R5's D-split broke
// this). 512 threads x float2: window 40xfloat2 = 80 VGPR -> <=128 total ->
// 2 blocks/CU = 16 waves/CU, double R3's occupancy at the same halo ratio.

constexpr int B_ = 4;
constexpr int S_ = 4096;
constexpr int D_ = 1024;
constexpr int MAXD  = 8;
constexpr int CHUNK = 32;
constexpr int ROWS  = CHUNK + MAXD;      // 40-row register window
constexpr int NDIFF = ROWS - 1;          // 39 adjacent diffs
constexpr int NCH   = S_ / CHUNK;        // 128 s-chunks
constexpr int NWG   = B_ * NCH;          // 512 blocks
constexpr int NXCD  = 8;

__global__ __launch_bounds__(512, 4)
void traj_splat_kernel(const float* __restrict__ emb, float* __restrict__ out) {
    // XCD swizzle (NWG % 8 == 0 -> bijective): consecutive lin on one XCD are
    // consecutive s-chunks -> 8-row halo is an L2 hit.
    const int bid = blockIdx.x;
    const int lin = (bid % NXCD) * (NWG / NXCD) + bid / NXCD;
    const int schunk = lin & (NCH - 1);
    const int b      = lin >> 7;

    const int s0   = schunk * CHUNK;
    const int lane = threadIdx.x & 63;
    const int wave = threadIdx.x >> 6;    // 8 waves
    const int d0   = threadIdx.x * 2;     // 512 threads * 2 floats = 1024 = D

    const float* __restrict__ embB = emb + (size_t)b * S_ * D_;

    __shared__ float part[NDIFF][33];     // 32 partials/diff, +1 pad (diag banks)
    __shared__ float smagw[NDIFF];
    __shared__ float sq[NDIFF];
    __shared__ float gco[CHUNK][12];

    // ---- Phase A: 40-row window, float2/thread (independent loads, ILP) ----
    float2 win[ROWS];
    #pragma unroll
    for (int r = 0; r < ROWS; ++r) {
        const int row = s0 - MAXD + r;    // max = s0+31 <= S-1
        win[r] = (row >= 0) ? *(const float2*)(embB + (size_t)row * D_ + d0)
                            : make_float2(0.f, 0.f);
    }

    // ---- Phase B: 39 full-D diff magnitudes; 4-level butterfly -> 4/wave ----
    #pragma unroll
    for (int li = 0; li < NDIFF; ++li) {
        const float2 a = win[li], c = win[li + 1];
        const float dx = c.x - a.x, dy = c.y - a.y;
        float sum = dx * dx + dy * dy;
        sum += __shfl_xor(sum, 32, 64);
        sum += __shfl_xor(sum, 16, 64);
        sum += __shfl_xor(sum,  8, 64);
        sum += __shfl_xor(sum,  4, 64);
        if (lane < 4) part[li][wave * 4 + lane] = sum;  // 8 waves * 4 = 32
    }
    __syncthreads();

    if (threadIdx.x < NDIFF) {
        const int li = threadIdx.x;
        float s2 = 0.f;
        #pragma unroll
        for (int k = 0; k < 32; ++k) s2 += part[li][k];  // stride-33 rows: no conflict
        const float mag = sqrtf(s2);                     // FULL-D magnitude
        const float mw  = tanhf(2.f * mag);
        smagw[li] = mw;
        sq[li]    = (mag > 1e-6f) ? (mw / mag) : 0.f;
    }
    __syncthreads();

    // ---- Phase C1: CHUNK threads build the 9 telescoped coefficients per s ----
    if (threadIdx.x < CHUNK) {
        const int sl = threadIdx.x;
        const int s  = s0 + sl;
        const int ws = min(MAXD, s);
        const int lo = MAXD - ws;
        const float rden = 0.9f / (float)max(ws - 1, 1);

        float cpad[MAXD + 2];
        #pragma unroll
        for (int t = 0; t < MAXD + 2; ++t) cpad[t] = 0.f;

        float wsum = 0.f;
        #pragma unroll
        for (int j = 0; j < MAXD; ++j) {
            if (j >= lo) {
                const int li = sl + j;               // diff at global index s-8+j
                const float lin2 = (ws > 1) ? (0.1f + rden * (float)(j - lo)) : 0.1f;
                wsum += lin2 * smagw[li];
                cpad[j + 1] = lin2 * sq[li];
            }
        }
        const float inv = 1.f / fmaxf(wsum, 1e-8f);
        #pragma unroll
        for (int jr = 0; jr <= MAXD; ++jr)
            gco[sl][jr] = (cpad[jr] - cpad[jr + 1]) * inv;
    }
    __syncthreads();

    // ---- Phase C2: outputs from registers, broadcast coefficient reads ----
    float* outB = out + ((size_t)b * S_ + s0) * D_ + d0;
    #pragma unroll
    for (int sl = 0; sl < CHUNK; ++sl) {
        const float4 g0 = *(const float4*)&gco[sl][0];   // g[0..3] (broadcast)
        const float4 g1 = *(const float4*)&gco[sl][4];   // g[4..7]
        const float  g8 = gco[sl][8];

        float2 acc;
        acc.x = g0.x * win[sl].x;
        acc.y = g0.x * win[sl].y;
        const float gs[8] = {g0.y, g0.z, g0.w, g1.x, g1.y, g1.z, g1.w, g8};
        #pragma unroll
        for (int jr = 1; jr <= MAXD; ++jr) {
            const float g = gs[jr - 1];
            acc.x += g * win[sl + jr].x;
            acc.y += g * win[sl + jr].y;
        }
        *(float2*)(outB + (size_t)sl * D_) = acc;
    }
}

extern "C" void kernel_launch(void* const* d_in, const int* in_sizes, int n_in,
                              void* d_out, int out_size, void* d_ws, size_t ws_size,
                              hipStream_t stream) {
    const float* emb = (const float*)d_in[0];
    float* out = (float*)d_out;

    dim3 grid(NWG);      // 512 blocks, swizzled in-kernel
    dim3 block(512);
    traj_splat_kernel<<<grid, block, 0, stream>>>(emb, out);
}